// Round 6
// baseline (396.031 us; speedup 1.0000x reference)
//
#include <hip/hip_runtime.h>
#include <math.h>

// Problem constants (match reference)
#define B_TOK 16384
#define H_DIM 2048
#define NE    8
#define TOPK  2
#define HFD   512

// Expert-kernel tiling
#define TN 128    // pos (token-slot) tile per block
#define BK 32     // K chunk per pipeline stage
#define NKSTEP (H_DIM / BK)   // 64

// Workspace layout (bytes)
static constexpr size_t OFF_COUNTS = 0;           // 32 B
static constexpr size_t OFF_CBASE  = 128;         // cbase[8] + cpad[8] ints
static constexpr size_t OFF_BUCKET = 1024;        // 512 KB -> 525312
static constexpr size_t OFF_WSLOT  = 525312;      // 128 KB -> 656384
static constexpr size_t OFF_ROUTE  = 656384;      // 64 KB  -> 721920
static constexpr size_t OFF_INV    = 721920;      // 128 KB -> 852992
static constexpr size_t OFF_WGT    = 860160;      // 64 KB  -> 925696
static constexpr size_t OFF_P      = 925696;      // 33792 floats -> 1060864
static constexpr size_t OFF_W1TS   = 2u << 20;    // 16 MB  -> 18874368
static constexpr size_t OFF_XGT    = 18874368;    // 33792 rows * 4 KB = 132 MB
// total ws use ~150 MB

typedef short bfrag __attribute__((ext_vector_type(8)));   // 8 bf16 (4 VGPR)
typedef float facc  __attribute__((ext_vector_type(16)));  // 32x32 accum

// fp32 -> bf16 (round-to-nearest-even)
__device__ inline unsigned short f2bf(float f) {
    union { float f; unsigned u; } v; v.f = f;
    unsigned r = v.u + 0x7FFFu + ((v.u >> 16) & 1u);
    return (unsigned short)(r >> 16);
}
__device__ inline unsigned pack2(float lo, float hi) {
    return (unsigned)f2bf(lo) | ((unsigned)f2bf(hi) << 16);
}

__device__ __forceinline__ void gload_lds16(const void* g, void* l) {
    __builtin_amdgcn_global_load_lds(
        (const __attribute__((address_space(1))) unsigned int*)g,
        (__attribute__((address_space(3))) unsigned int*)l, 16, 0, 0);
}

// ---------------------------------------------------------------------------
// Transpose gate weights: Wg [H][E] -> WgT [E][H].
// ---------------------------------------------------------------------------
__global__ __launch_bounds__(256)
void wg_transpose_kernel(const float* __restrict__ Wg,
                         float* __restrict__ WgT)
{
    const int t = threadIdx.x;
    #pragma unroll
    for (int rep = 0; rep < H_DIM / 256; ++rep) {
        const int h = rep * 256 + t;
        const float4 a = *reinterpret_cast<const float4*>(Wg + (size_t)h * NE);
        const float4 b = *reinterpret_cast<const float4*>(Wg + (size_t)h * NE + 4);
        WgT[0 * H_DIM + h] = a.x;  WgT[1 * H_DIM + h] = a.y;
        WgT[2 * H_DIM + h] = a.z;  WgT[3 * H_DIM + h] = a.w;
        WgT[4 * H_DIM + h] = b.x;  WgT[5 * H_DIM + h] = b.y;
        WgT[6 * H_DIM + h] = b.z;  WgT[7 * H_DIM + h] = b.w;
    }
}

// ---------------------------------------------------------------------------
// Prep W1: [E][H][HF] fp32 -> k-slot-major bf16 image:
//   W1ts[e][kstep(64)][slot(4)][f(512)][j(8)]   (k = kstep*32 + slot*8 + j)
// Each (e,kstep) 32 KB block is exactly one expert-kernel A-stage image.
// ---------------------------------------------------------------------------
__global__ __launch_bounds__(256)
void prep_w1_kernel(const float* __restrict__ W1,
                    unsigned short* __restrict__ W1ts)
{
    const int blk   = blockIdx.x;       // e*64 + kstep
    const int e     = blk >> 6;
    const int kstep = blk & 63;
    const int tid   = threadIdx.x;

    const float* src = W1 + ((size_t)e * H_DIM + kstep * BK) * HFD;
    unsigned short* dst = W1ts + (size_t)e * (HFD * H_DIM) + (size_t)kstep * (BK * HFD);

    #pragma unroll
    for (int s = 0; s < 4; ++s) {
        #pragma unroll
        for (int fh = 0; fh < 2; ++fh) {
            const int f = fh * 256 + tid;
            float v[8];
            #pragma unroll
            for (int j = 0; j < 8; ++j)
                v[j] = src[(size_t)(s * 8 + j) * HFD + f];   // coalesced across lanes
            uint4 p;
            p.x = pack2(v[0], v[1]); p.y = pack2(v[2], v[3]);
            p.z = pack2(v[4], v[5]); p.w = pack2(v[6], v[7]);
            *reinterpret_cast<uint4*>(dst + s * 4096 + f * 8) = p;
        }
    }
}

// ---------------------------------------------------------------------------
// Gate logits (atomic-free). One wave per token, float4 loads.
// ---------------------------------------------------------------------------
__global__ __launch_bounds__(256)
void gate_logits_kernel(const float* __restrict__ x,
                        const float* __restrict__ WgT,
                        const float* __restrict__ bg,
                        float* __restrict__ out_logits,
                        float* __restrict__ wslot,
                        int*   __restrict__ route)
{
    const int tok  = (blockIdx.x * blockDim.x + threadIdx.x) >> 6;
    const int lane = threadIdx.x & 63;
    if (tok >= B_TOK) return;

    const float* xrow = x + (size_t)tok * H_DIM;

    float acc[NE];
    #pragma unroll
    for (int e = 0; e < NE; ++e) acc[e] = 0.f;

    #pragma unroll 2
    for (int i = 0; i < H_DIM / 256; ++i) {
        const int h = i * 256 + 4 * lane;
        const float4 xv = *reinterpret_cast<const float4*>(xrow + h);
        #pragma unroll
        for (int e = 0; e < NE; ++e) {
            const float4 wv = *reinterpret_cast<const float4*>(WgT + (size_t)e * H_DIM + h);
            acc[e] += xv.x * wv.x + xv.y * wv.y + xv.z * wv.z + xv.w * wv.w;
        }
    }

    #pragma unroll
    for (int e = 0; e < NE; ++e) {
        #pragma unroll
        for (int off = 32; off > 0; off >>= 1)
            acc[e] += __shfl_xor(acc[e], off, 64);
    }

    if (lane == 0) {
        #pragma unroll
        for (int e = 0; e < NE; ++e) acc[e] += bg[e];

        float4* lo = reinterpret_cast<float4*>(out_logits + (size_t)tok * NE);
        lo[0] = make_float4(acc[0], acc[1], acc[2], acc[3]);
        lo[1] = make_float4(acc[4], acc[5], acc[6], acc[7]);

        int i0 = 0; float v0 = acc[0];
        #pragma unroll
        for (int e = 1; e < NE; ++e)
            if (acc[e] > v0) { v0 = acc[e]; i0 = e; }
        int i1 = -1; float v1 = -3.4e38f;
        #pragma unroll
        for (int e = 0; e < NE; ++e)
            if (e != i0 && acc[e] > v1) { v1 = acc[e]; i1 = e; }

        const float w0 = 1.f / (1.f + expf(v1 - v0));
        wslot[tok * 2]     = w0;
        wslot[tok * 2 + 1] = 1.f - w0;
        route[tok] = i0 | (i1 << 8);
    }
}

// ---------------------------------------------------------------------------
// Route/bucket: LDS-aggregated histogram; 8 global atomics per block.
// ---------------------------------------------------------------------------
__global__ __launch_bounds__(1024)
void route_kernel(const int* __restrict__ route,
                  int* __restrict__ counts,
                  int* __restrict__ bucket)
{
    __shared__ int lcnt[NE];
    __shared__ int lbase[NE];
    const int tid = threadIdx.x;
    const int tok = blockIdx.x * 1024 + tid;

    if (tid < NE) lcnt[tid] = 0;
    __syncthreads();

    const int rt = route[tok];
    const int i0 = rt & 255;
    const int i1 = rt >> 8;
    const int r0 = atomicAdd(&lcnt[i0], 1);
    const int r1 = atomicAdd(&lcnt[i1], 1);
    __syncthreads();

    if (tid < NE) lbase[tid] = atomicAdd(&counts[tid], lcnt[tid]);
    __syncthreads();

    bucket[i0 * B_TOK + lbase[i0] + r0] = tok * 2;
    bucket[i1 * B_TOK + lbase[i1] + r1] = tok * 2 + 1;
}

// ---------------------------------------------------------------------------
// Prefix: cbase[e] = row base of expert region; cpad[e] = count padded to 128.
// ---------------------------------------------------------------------------
__global__ void prefix_kernel(const int* __restrict__ counts,
                              int* __restrict__ cbase)
{
    if (threadIdx.x == 0 && blockIdx.x == 0) {
        int acc = 0;
        for (int e = 0; e < NE; ++e) {
            const int cp = ((counts[e] + 127) >> 7) << 7;
            cbase[e]      = acc;
            cbase[NE + e] = cp;
            acc += cp;
        }
    }
}

// ---------------------------------------------------------------------------
// X gather/transpose: for expert e, pos tile of 64 tokens, write the
// k-slot-major image  xgT[cbase[e] rows][kstep(64)][slot(4)][pos][j(8)]
// (row-granular: elem offset = cb*2048 + ((kstep*4+slot)*cpad + pos)*8).
// Reads x rows coalesced (64B/thread), LDS transpose, 1 KB coalesced stores.
// Also writes inv[entry] = global row index (for the combine kernel).
// ---------------------------------------------------------------------------
__global__ __launch_bounds__(256)
void xgather_kernel(const float* __restrict__ x,
                    const int* __restrict__ bucket,
                    const int* __restrict__ counts,
                    const int* __restrict__ cbase,
                    unsigned short* __restrict__ xgT,
                    int* __restrict__ inv)
{
    const int e    = blockIdx.x & 7;
    const int tile = blockIdx.x >> 3;        // 0..511
    const int n    = counts[e];
    const int pos0 = tile * 64;
    if (pos0 >= n) return;
    const int cb   = cbase[e];
    const size_t cpad = (size_t)cbase[NE + e];
    const int t = threadIdx.x;

    __shared__ int toks[64];
    __shared__ unsigned short T[8][64][8];   // 8 KB

    if (t < 64) {
        const int pos = pos0 + t;
        const int entry = bucket[e * B_TOK + min(pos, n - 1)];
        toks[t] = entry >> 1;
        if (pos < n) inv[entry] = cb + pos;
    }
    __syncthreads();

    const int p = t >> 2;     // local pos 0..63
    const int q = t & 3;      // 16-float quarter of the 64-k chunk
    const float* src = x + (size_t)toks[p] * H_DIM + q * 16;
    unsigned short* dstbase = xgT + (size_t)cb * H_DIM;

    for (int kc = 0; kc < 32; ++kc) {        // 64 k per chunk
        const float4 v0 = *reinterpret_cast<const float4*>(src + kc * 64);
        const float4 v1 = *reinterpret_cast<const float4*>(src + kc * 64 + 4);
        const float4 v2 = *reinterpret_cast<const float4*>(src + kc * 64 + 8);
        const float4 v3 = *reinterpret_cast<const float4*>(src + kc * 64 + 12);
        uint4 pa, pb;
        pa.x = pack2(v0.x, v0.y); pa.y = pack2(v0.z, v0.w);
        pa.z = pack2(v1.x, v1.y); pa.w = pack2(v1.z, v1.w);
        pb.x = pack2(v2.x, v2.y); pb.y = pack2(v2.z, v2.w);
        pb.z = pack2(v3.x, v3.y); pb.w = pack2(v3.z, v3.w);
        __syncthreads();                     // prev iteration's out-reads done
        *reinterpret_cast<uint4*>(&T[q * 2][p][0])     = pa;
        *reinterpret_cast<uint4*>(&T[q * 2 + 1][p][0]) = pb;
        __syncthreads();
        #pragma unroll
        for (int g = 0; g < 2; ++g) {
            const int u   = t + g * 256;
            const int s8  = u >> 6;          // 0..7
            const int pp  = u & 63;
            const int kst = 2 * kc + (s8 >> 2);
            const int sl  = s8 & 3;
            *reinterpret_cast<uint4*>(
                dstbase + ((size_t)(kst * 4 + sl) * cpad + pos0 + pp) * 8) =
                *reinterpret_cast<const uint4*>(&T[s8][pp][0]);
        }
    }
}

// ---------------------------------------------------------------------------
// Expert MFMA kernel: dense per-expert GEMM on pre-gathered operands.
// M=512 (all f), N=128 pos, BK=32, double-buffered; per step each wave
// issues exactly 5 LINEAR global_load_lds (4 A + 1 X), vmcnt(5) in loop.
// 8 waves: wm = w&3 (128 f rows), wn = w>>2 (64 pos cols); 4x2 frags,
// 16 MFMA/step. Writes P[gs] once (no atomics). e = blockIdx&7 XCD-pins W1.
// ---------------------------------------------------------------------------
__global__ __launch_bounds__(512, 2)
void expert_mfma_kernel(const unsigned short* __restrict__ xgT,
                        const unsigned short* __restrict__ W1ts,
                        const float* __restrict__ b1,
                        const float* __restrict__ W2,
                        const int* __restrict__ counts,
                        const int* __restrict__ cbase,
                        float* __restrict__ P)
{
    const int e  = blockIdx.x & 7;
    const int pt = blockIdx.x >> 3;          // 0..255
    const int n  = counts[e];
    const int pos0 = pt * TN;
    if (pos0 >= n) return;
    const int nt = min(TN, n - pos0);
    const int cb = cbase[e];
    const size_t cpad = (size_t)cbase[NE + e];

    __shared__ __align__(16) unsigned char smem[81920];  // 2x32KB A + 2x8KB X
    unsigned short* const Ab = (unsigned short*)smem;            // [2][16384]
    unsigned short* const Xb = (unsigned short*)(smem + 65536);  // [2][4096]
    float* const o_part = (float*)smem;                          // overlay

    const int tid = threadIdx.x;
    const int w   = tid >> 6;
    const int l   = tid & 63;
    const int lo5 = l & 31;
    const int hi  = l >> 5;
    const int wm  = w & 3;       // f-group (128 rows)
    const int wn  = w >> 2;      // pos-group (64 cols)

    const unsigned short* W1e  = W1ts + (size_t)e * (HFD * H_DIM);
    const unsigned short* xg_e = xgT + (size_t)cb * H_DIM;
    const int xslot = w >> 1;
    const int xhalf = w & 1;

    facc acc[4][2];
    #pragma unroll
    for (int m = 0; m < 4; ++m)
        #pragma unroll
        for (int nb = 0; nb < 2; ++nb)
            #pragma unroll
            for (int r = 0; r < 16; ++r) acc[m][nb][r] = 0.f;

    // 4 A-chunks (linear 32 KB copy) + 1 X-chunk per wave = 5 loads/stage
    #define STAGE(KK, S) do {                                                  \
        const unsigned short* asrc_ = W1e + (size_t)(KK) * 16384;              \
        unsigned short* adst_ = Ab + (S) * 16384;                              \
        const int o0_ = (w * 4 + 0) * 512 + l * 8;                             \
        const int o1_ = (w * 4 + 1) * 512 + l * 8;                             \
        const int o2_ = (w * 4 + 2) * 512 + l * 8;                             \
        const int o3_ = (w * 4 + 3) * 512 + l * 8;                             \
        gload_lds16(asrc_ + o0_, adst_ + o0_);                                 \
        gload_lds16(asrc_ + o1_, adst_ + o1_);                                 \
        gload_lds16(asrc_ + o2_, adst_ + o2_);                                 \
        gload_lds16(asrc_ + o3_, adst_ + o3_);                                 \
        gload_lds16(xg_e + ((size_t)((KK) * 4 + xslot) * cpad                  \
                            + pos0 + xhalf * 64 + l) * 8,                      \
                    Xb + (S) * 4096 + w * 512 + l * 8);                        \
    } while (0)

    STAGE(0, 0);

    for (int kk = 0; kk < NKSTEP; ++kk) {
        const int cur = kk & 1;
        if (kk + 1 < NKSTEP) {
            STAGE(kk + 1, cur ^ 1);
            asm volatile("s_waitcnt vmcnt(5)" ::: "memory");
        } else {
            asm volatile("s_waitcnt vmcnt(0)" ::: "memory");
        }
        __builtin_amdgcn_s_barrier();

        __builtin_amdgcn_s_setprio(1);
        #pragma unroll
        for (int ks = 0; ks < 2; ++ks) {
            const int slot = ks * 2 + hi;
            bfrag a[4], bb[2];
            #pragma unroll
            for (int m = 0; m < 4; ++m)
                a[m] = *reinterpret_cast<const bfrag*>(
                    Ab + cur * 16384 + slot * 4096 + (wm * 128 + m * 32 + lo5) * 8);
            #pragma unroll
            for (int nb = 0; nb < 2; ++nb)
                bb[nb] = *reinterpret_cast<const bfrag*>(
                    Xb + cur * 4096 + slot * 1024 + (wn * 64 + nb * 32 + lo5) * 8);
            #pragma unroll
            for (int m = 0; m < 4; ++m)
                #pragma unroll
                for (int nb = 0; nb < 2; ++nb)
                    acc[m][nb] = __builtin_amdgcn_mfma_f32_32x32x16_bf16(
                        a[m], bb[nb], acc[m][nb], 0, 0, 0);
        }
        __builtin_amdgcn_s_setprio(0);
        __builtin_amdgcn_s_barrier();
    }
    #undef STAGE

    // Epilogue: bias + exact GELU + W2 dot; reduce over f.
    const float* b1e = b1 + e * HFD;
    const float* W2e = W2 + e * HFD;
    const float kInvSqrt2 = 0.70710678118654752f;

    float po0 = 0.f, po1 = 0.f;
    #pragma unroll
    for (int m = 0; m < 4; ++m) {
        const int base = wm * 128 + m * 32 + 4 * hi;
        #pragma unroll
        for (int r = 0; r < 16; ++r) {
            const int frow = base + (r & 3) + 8 * (r >> 2);
            const float bv = b1e[frow];
            const float wv = W2e[frow];
            const float h0 = acc[m][0][r] + bv;
            const float h1 = acc[m][1][r] + bv;
            po0 += 0.5f * h0 * (1.f + erff(h0 * kInvSqrt2)) * wv;
            po1 += 0.5f * h1 * (1.f + erff(h1 * kInvSqrt2)) * wv;
        }
    }
    po0 += __shfl_xor(po0, 32, 64);
    po1 += __shfl_xor(po1, 32, 64);

    // o_part overlays Ab (safe: all LDS reads retired at the final barrier)
    if (hi == 0) {
        o_part[wm * TN + wn * 64 + lo5]      = po0;
        o_part[wm * TN + wn * 64 + 32 + lo5] = po1;
    }
    __syncthreads();

    if (tid < nt) {
        P[cb + pos0 + tid] = o_part[0 * TN + tid] + o_part[1 * TN + tid]
                           + o_part[2 * TN + tid] + o_part[3 * TN + tid];
    }
}

// ---------------------------------------------------------------------------
// Combine: out[t] = w0 * P[gs0] + w1 * P[gs1].  No atomics, deterministic.
// ---------------------------------------------------------------------------
__global__ __launch_bounds__(256)
void combine_kernel(const int* __restrict__ inv,
                    const float* __restrict__ P,
                    const float* __restrict__ wslot,
                    float* __restrict__ out_scores)
{
    const int t = blockIdx.x * 256 + threadIdx.x;
    if (t >= B_TOK) return;
    out_scores[t] = wslot[2 * t]     * P[inv[2 * t]]
                  + wslot[2 * t + 1] * P[inv[2 * t + 1]];
}

// ---------------------------------------------------------------------------
extern "C" void kernel_launch(void* const* d_in, const int* in_sizes, int n_in,
                              void* d_out, int out_size, void* d_ws, size_t ws_size,
                              hipStream_t stream)
{
    const float* x  = (const float*)d_in[0];   // [B, H]
    const float* W1 = (const float*)d_in[1];   // [E, H, HF]
    const float* b1 = (const float*)d_in[2];   // [E, HF]
    const float* W2 = (const float*)d_in[3];   // [E, HF]
    const float* Wg = (const float*)d_in[4];   // [H, E]
    const float* bg = (const float*)d_in[5];   // [E]

    float* out        = (float*)d_out;
    float* out_scores = out;                   // [B, 1]
    float* out_logits = out + B_TOK;           // [B, E]

    char* ws = (char*)d_ws;
    int*            counts = (int*)           (ws + OFF_COUNTS);
    int*            cbase  = (int*)           (ws + OFF_CBASE);
    int*            bucket = (int*)           (ws + OFF_BUCKET);
    float*          wslot  = (float*)         (ws + OFF_WSLOT);
    int*            route  = (int*)           (ws + OFF_ROUTE);
    int*            inv    = (int*)           (ws + OFF_INV);
    float*          WgT    = (float*)         (ws + OFF_WGT);
    float*          P      = (float*)         (ws + OFF_P);
    unsigned short* W1ts   = (unsigned short*)(ws + OFF_W1TS);
    unsigned short* xgT    = (unsigned short*)(ws + OFF_XGT);

    hipMemsetAsync(counts, 0, NE * sizeof(int), stream);

    wg_transpose_kernel<<<1, 256, 0, stream>>>(Wg, WgT);

    prep_w1_kernel<<<NE * NKSTEP, 256, 0, stream>>>(W1, W1ts);

    gate_logits_kernel<<<B_TOK / 4, 256, 0, stream>>>(x, WgT, bg, out_logits,
                                                      wslot, route);

    route_kernel<<<B_TOK / 1024, 1024, 0, stream>>>(route, counts, bucket);

    prefix_kernel<<<1, 64, 0, stream>>>(counts, cbase);

    xgather_kernel<<<NE * (B_TOK * 2 / 64), 256, 0, stream>>>(
        x, bucket, counts, cbase, xgT, inv);

    expert_mfma_kernel<<<NE * (B_TOK * 2 / TN), 512, 0, stream>>>(
        xgT, W1ts, b1, W2, counts, cbase, P);

    combine_kernel<<<B_TOK / 256, 256, 0, stream>>>(inv, P, wslot, out_scores);
}

// Round 7
// 394.394 us; speedup vs baseline: 1.0042x; 1.0042x over previous
//
#include <hip/hip_runtime.h>
#include <math.h>

// Problem constants (match reference)
#define B_TOK 16384
#define H_DIM 2048
#define NE    8
#define TOPK  2
#define HFD   512

// Expert-kernel tiling
#define TM 256    // f rows per block tile (2 M-tiles cover HFD=512)
#define TN 128    // pos (token-slot) tile per block
#define BK 32     // K chunk per pipeline stage
#define NKSTEP (H_DIM / BK)   // 64

// Workspace layout (bytes)
static constexpr size_t OFF_COUNTS = 0;           // 32 B
static constexpr size_t OFF_CBASE  = 128;         // cbase[8] + cpad[8] ints
static constexpr size_t OFF_BUCKET = 1024;        // 512 KB -> 525312
static constexpr size_t OFF_WSLOT  = 525312;      // 128 KB -> 656384
static constexpr size_t OFF_ROUTE  = 656384;      // 64 KB  -> 721920
static constexpr size_t OFF_INV    = 721920;      // 128 KB -> 852992
static constexpr size_t OFF_WGT    = 860160;      // 64 KB  -> 925696
static constexpr size_t OFF_P      = 925696;      // 33792 floats -> 1060864
static constexpr size_t OFF_W1TS   = 2u << 20;    // 16 MB  -> 18874368
static constexpr size_t OFF_XGT    = 18874368;    // 33792 rows * 4 KB = 132 MB
// total ws use ~150 MB

typedef short bfrag __attribute__((ext_vector_type(8)));   // 8 bf16 (4 VGPR)
typedef float facc  __attribute__((ext_vector_type(16)));  // 32x32 accum

// fp32 -> bf16 (round-to-nearest-even)
__device__ inline unsigned short f2bf(float f) {
    union { float f; unsigned u; } v; v.f = f;
    unsigned r = v.u + 0x7FFFu + ((v.u >> 16) & 1u);
    return (unsigned short)(r >> 16);
}
__device__ inline unsigned pack2(float lo, float hi) {
    return (unsigned)f2bf(lo) | ((unsigned)f2bf(hi) << 16);
}

__device__ __forceinline__ void gload_lds16(const void* g, void* l) {
    __builtin_amdgcn_global_load_lds(
        (const __attribute__((address_space(1))) unsigned int*)g,
        (__attribute__((address_space(3))) unsigned int*)l, 16, 0, 0);
}

// ---------------------------------------------------------------------------
// Transpose gate weights: Wg [H][E] -> WgT [E][H].
// ---------------------------------------------------------------------------
__global__ __launch_bounds__(256)
void wg_transpose_kernel(const float* __restrict__ Wg,
                         float* __restrict__ WgT)
{
    const int t = threadIdx.x;
    #pragma unroll
    for (int rep = 0; rep < H_DIM / 256; ++rep) {
        const int h = rep * 256 + t;
        const float4 a = *reinterpret_cast<const float4*>(Wg + (size_t)h * NE);
        const float4 b = *reinterpret_cast<const float4*>(Wg + (size_t)h * NE + 4);
        WgT[0 * H_DIM + h] = a.x;  WgT[1 * H_DIM + h] = a.y;
        WgT[2 * H_DIM + h] = a.z;  WgT[3 * H_DIM + h] = a.w;
        WgT[4 * H_DIM + h] = b.x;  WgT[5 * H_DIM + h] = b.y;
        WgT[6 * H_DIM + h] = b.z;  WgT[7 * H_DIM + h] = b.w;
    }
}

// ---------------------------------------------------------------------------
// Prep W1: [E][H][HF] fp32 -> k-slot-major bf16 image:
//   W1ts[e][kstep(64)][slot(4)][f(512)][j(8)]   (k = kstep*32 + slot*8 + j)
// Each (e,kstep) 32 KB block is exactly one expert-kernel A-stage image.
// ---------------------------------------------------------------------------
__global__ __launch_bounds__(256)
void prep_w1_kernel(const float* __restrict__ W1,
                    unsigned short* __restrict__ W1ts)
{
    const int blk   = blockIdx.x;       // e*64 + kstep
    const int e     = blk >> 6;
    const int kstep = blk & 63;
    const int tid   = threadIdx.x;

    const float* src = W1 + ((size_t)e * H_DIM + kstep * BK) * HFD;
    unsigned short* dst = W1ts + (size_t)e * (HFD * H_DIM) + (size_t)kstep * (BK * HFD);

    #pragma unroll
    for (int s = 0; s < 4; ++s) {
        #pragma unroll
        for (int fh = 0; fh < 2; ++fh) {
            const int f = fh * 256 + tid;
            float v[8];
            #pragma unroll
            for (int j = 0; j < 8; ++j)
                v[j] = src[(size_t)(s * 8 + j) * HFD + f];   // coalesced across lanes
            uint4 p;
            p.x = pack2(v[0], v[1]); p.y = pack2(v[2], v[3]);
            p.z = pack2(v[4], v[5]); p.w = pack2(v[6], v[7]);
            *reinterpret_cast<uint4*>(dst + s * 4096 + f * 8) = p;
        }
    }
}

// ---------------------------------------------------------------------------
// Gate logits (atomic-free). One wave per token, float4 loads.
// ---------------------------------------------------------------------------
__global__ __launch_bounds__(256)
void gate_logits_kernel(const float* __restrict__ x,
                        const float* __restrict__ WgT,
                        const float* __restrict__ bg,
                        float* __restrict__ out_logits,
                        float* __restrict__ wslot,
                        int*   __restrict__ route)
{
    const int tok  = (blockIdx.x * blockDim.x + threadIdx.x) >> 6;
    const int lane = threadIdx.x & 63;
    if (tok >= B_TOK) return;

    const float* xrow = x + (size_t)tok * H_DIM;

    float acc[NE];
    #pragma unroll
    for (int e = 0; e < NE; ++e) acc[e] = 0.f;

    #pragma unroll 2
    for (int i = 0; i < H_DIM / 256; ++i) {
        const int h = i * 256 + 4 * lane;
        const float4 xv = *reinterpret_cast<const float4*>(xrow + h);
        #pragma unroll
        for (int e = 0; e < NE; ++e) {
            const float4 wv = *reinterpret_cast<const float4*>(WgT + (size_t)e * H_DIM + h);
            acc[e] += xv.x * wv.x + xv.y * wv.y + xv.z * wv.z + xv.w * wv.w;
        }
    }

    #pragma unroll
    for (int e = 0; e < NE; ++e) {
        #pragma unroll
        for (int off = 32; off > 0; off >>= 1)
            acc[e] += __shfl_xor(acc[e], off, 64);
    }

    if (lane == 0) {
        #pragma unroll
        for (int e = 0; e < NE; ++e) acc[e] += bg[e];

        float4* lo = reinterpret_cast<float4*>(out_logits + (size_t)tok * NE);
        lo[0] = make_float4(acc[0], acc[1], acc[2], acc[3]);
        lo[1] = make_float4(acc[4], acc[5], acc[6], acc[7]);

        int i0 = 0; float v0 = acc[0];
        #pragma unroll
        for (int e = 1; e < NE; ++e)
            if (acc[e] > v0) { v0 = acc[e]; i0 = e; }
        int i1 = -1; float v1 = -3.4e38f;
        #pragma unroll
        for (int e = 0; e < NE; ++e)
            if (e != i0 && acc[e] > v1) { v1 = acc[e]; i1 = e; }

        const float w0 = 1.f / (1.f + expf(v1 - v0));
        wslot[tok * 2]     = w0;
        wslot[tok * 2 + 1] = 1.f - w0;
        route[tok] = i0 | (i1 << 8);
    }
}

// ---------------------------------------------------------------------------
// Route/bucket: LDS-aggregated histogram; 8 global atomics per block.
// ---------------------------------------------------------------------------
__global__ __launch_bounds__(1024)
void route_kernel(const int* __restrict__ route,
                  int* __restrict__ counts,
                  int* __restrict__ bucket)
{
    __shared__ int lcnt[NE];
    __shared__ int lbase[NE];
    const int tid = threadIdx.x;
    const int tok = blockIdx.x * 1024 + tid;

    if (tid < NE) lcnt[tid] = 0;
    __syncthreads();

    const int rt = route[tok];
    const int i0 = rt & 255;
    const int i1 = rt >> 8;
    const int r0 = atomicAdd(&lcnt[i0], 1);
    const int r1 = atomicAdd(&lcnt[i1], 1);
    __syncthreads();

    if (tid < NE) lbase[tid] = atomicAdd(&counts[tid], lcnt[tid]);
    __syncthreads();

    bucket[i0 * B_TOK + lbase[i0] + r0] = tok * 2;
    bucket[i1 * B_TOK + lbase[i1] + r1] = tok * 2 + 1;
}

// ---------------------------------------------------------------------------
// Prefix: cbase[e] = row base of expert region; cpad[e] = count padded to 128.
// ---------------------------------------------------------------------------
__global__ void prefix_kernel(const int* __restrict__ counts,
                              int* __restrict__ cbase)
{
    if (threadIdx.x == 0 && blockIdx.x == 0) {
        int acc = 0;
        for (int e = 0; e < NE; ++e) {
            const int cp = ((counts[e] + 127) >> 7) << 7;
            cbase[e]      = acc;
            cbase[NE + e] = cp;
            acc += cp;
        }
    }
}

// ---------------------------------------------------------------------------
// X gather/transpose: for expert e, pos tile of 64 tokens, write the
// k-slot-major image  xgT[cbase[e] rows][kstep(64)][slot(4)][pos][j(8)].
// Reads x rows coalesced, LDS transpose, 1 KB coalesced stores.
// Also writes inv[entry] = global row index (for the combine kernel).
// ---------------------------------------------------------------------------
__global__ __launch_bounds__(256)
void xgather_kernel(const float* __restrict__ x,
                    const int* __restrict__ bucket,
                    const int* __restrict__ counts,
                    const int* __restrict__ cbase,
                    unsigned short* __restrict__ xgT,
                    int* __restrict__ inv)
{
    const int e    = blockIdx.x & 7;
    const int tile = blockIdx.x >> 3;        // 0..255
    const int n    = counts[e];
    const int pos0 = tile * 64;
    if (pos0 >= n) return;
    const int cb   = cbase[e];
    const size_t cpad = (size_t)cbase[NE + e];
    const int t = threadIdx.x;

    __shared__ int toks[64];
    __shared__ unsigned short T[8][64][8];   // 8 KB

    if (t < 64) {
        const int pos = pos0 + t;
        const int entry = bucket[e * B_TOK + min(pos, n - 1)];
        toks[t] = entry >> 1;
        if (pos < n) inv[entry] = cb + pos;
    }
    __syncthreads();

    const int p = t >> 2;     // local pos 0..63
    const int q = t & 3;      // 16-float quarter of the 64-k chunk
    const float* src = x + (size_t)toks[p] * H_DIM + q * 16;
    unsigned short* dstbase = xgT + (size_t)cb * H_DIM;

    for (int kc = 0; kc < 32; ++kc) {        // 64 k per chunk
        const float4 v0 = *reinterpret_cast<const float4*>(src + kc * 64);
        const float4 v1 = *reinterpret_cast<const float4*>(src + kc * 64 + 4);
        const float4 v2 = *reinterpret_cast<const float4*>(src + kc * 64 + 8);
        const float4 v3 = *reinterpret_cast<const float4*>(src + kc * 64 + 12);
        uint4 pa, pb;
        pa.x = pack2(v0.x, v0.y); pa.y = pack2(v0.z, v0.w);
        pa.z = pack2(v1.x, v1.y); pa.w = pack2(v1.z, v1.w);
        pb.x = pack2(v2.x, v2.y); pb.y = pack2(v2.z, v2.w);
        pb.z = pack2(v3.x, v3.y); pb.w = pack2(v3.z, v3.w);
        __syncthreads();                     // prev iteration's out-reads done
        *reinterpret_cast<uint4*>(&T[q * 2][p][0])     = pa;
        *reinterpret_cast<uint4*>(&T[q * 2 + 1][p][0]) = pb;
        __syncthreads();
        #pragma unroll
        for (int g = 0; g < 2; ++g) {
            const int u   = t + g * 256;
            const int s8  = u >> 6;          // 0..7
            const int pp  = u & 63;
            const int kst = 2 * kc + (s8 >> 2);
            const int sl  = s8 & 3;
            *reinterpret_cast<uint4*>(
                dstbase + ((size_t)(kst * 4 + sl) * cpad + pos0 + pp) * 8) =
                *reinterpret_cast<const uint4*>(&T[s8][pp][0]);
        }
    }
}

// ---------------------------------------------------------------------------
// Expert MFMA kernel: dense per-expert GEMM on pre-gathered operands.
// 256 thr / 4 waves; tile M=256 (f half: mt), N=128 pos, BK=32.
// Simple 2-phase loop (proven m97/m248 structure): STAGE next into the
// static other-buffer, compute current, __syncthreads (compiler drains).
// Static A0/A1/X0/X1 buffers so the compiler disambiguates and only
// drains at the barrier. 49 KB LDS -> 2+ blocks/CU co-resident; grid is
// t-major so the ~512 working blocks land 2/CU. e = blockIdx&7 XCD-pins W1.
// ---------------------------------------------------------------------------
__global__ __launch_bounds__(256, 2)
void expert_mfma_kernel(const unsigned short* __restrict__ xgT,
                        const unsigned short* __restrict__ W1ts,
                        const float* __restrict__ b1,
                        const float* __restrict__ W2,
                        const int* __restrict__ counts,
                        const int* __restrict__ cbase,
                        float* __restrict__ P)
{
    const int e  = blockIdx.x & 7;
    const int t  = blockIdx.x >> 3;          // 0..255
    const int mt = t & 1;                    // f half: rows [mt*256, mt*256+256)
    const int pt = t >> 1;                   // pos tile
    const int n  = counts[e];
    const int pos0 = pt * TN;
    if (pos0 >= n) return;
    const int nt = min(TN, n - pos0);
    const int cb = cbase[e];
    const size_t cpad = (size_t)cbase[NE + e];

    __shared__ unsigned short A0[4 * 256 * 8];   // 16 KB  [slot][256 f][8]
    __shared__ unsigned short A1[4 * 256 * 8];   // 16 KB
    __shared__ unsigned short X0[4 * 128 * 8];   // 8 KB   [slot][128 pos][8]
    __shared__ unsigned short X1[4 * 128 * 8];   // 8 KB
    __shared__ float o_part[2][TN];              // 1 KB

    const int tid = threadIdx.x;
    const int w   = tid >> 6;    // wave 0..3
    const int l   = tid & 63;
    const int lo5 = l & 31;
    const int hi  = l >> 5;
    const int wm  = w & 1;       // f-group (128 rows)
    const int wn  = w >> 1;      // pos-group (64 cols)

    const unsigned short* W1e  = W1ts + (size_t)e * (HFD * H_DIM);
    const unsigned short* xg_e = xgT + (size_t)cb * H_DIM;

    facc acc[4][2];
    #pragma unroll
    for (int m = 0; m < 4; ++m)
        #pragma unroll
        for (int nb = 0; nb < 2; ++nb)
            #pragma unroll
            for (int r = 0; r < 16; ++r) acc[m][nb][r] = 0.f;

    // Per wave: 4 linear A loads (slot w, 4x 1KB) + 2 linear X loads.
    #define STAGE(KK, AB, XB) do {                                             \
        const unsigned short* as_ = W1e + (size_t)(KK) * 16384                 \
                                    + (w * 512 + mt * 256 + l) * 8;            \
        unsigned short* ad_ = AB + (w * 256 + l) * 8;                          \
        gload_lds16(as_,        ad_);                                          \
        gload_lds16(as_ +  512, ad_ +  512);                                   \
        gload_lds16(as_ + 1024, ad_ + 1024);                                   \
        gload_lds16(as_ + 1536, ad_ + 1536);                                   \
        const unsigned short* xs_ = xg_e                                       \
            + ((size_t)((KK) * 4 + w) * cpad + pos0 + l) * 8;                  \
        unsigned short* xd_ = XB + (w * 128 + l) * 8;                          \
        gload_lds16(xs_,       xd_);                                           \
        gload_lds16(xs_ + 512, xd_ + 512);                                     \
    } while (0)

    #define COMPUTE(AB, XB) do {                                               \
        _Pragma("unroll")                                                      \
        for (int ks = 0; ks < 2; ++ks) {                                       \
            const int slot = ks * 2 + hi;                                      \
            bfrag a[4], bb[2];                                                 \
            _Pragma("unroll")                                                  \
            for (int m = 0; m < 4; ++m)                                        \
                a[m] = *reinterpret_cast<const bfrag*>(                        \
                    AB + (slot * 256 + wm * 128 + m * 32 + lo5) * 8);          \
            _Pragma("unroll")                                                  \
            for (int nb = 0; nb < 2; ++nb)                                     \
                bb[nb] = *reinterpret_cast<const bfrag*>(                      \
                    XB + (slot * 128 + wn * 64 + nb * 32 + lo5) * 8);          \
            _Pragma("unroll")                                                  \
            for (int m = 0; m < 4; ++m)                                        \
                _Pragma("unroll")                                              \
                for (int nb = 0; nb < 2; ++nb)                                 \
                    acc[m][nb] = __builtin_amdgcn_mfma_f32_32x32x16_bf16(      \
                        a[m], bb[nb], acc[m][nb], 0, 0, 0);                    \
        }                                                                      \
    } while (0)

    STAGE(0, A0, X0);
    __syncthreads();                      // A0/X0 ready (compiler drains vmcnt)

    for (int kk = 0; kk < NKSTEP; kk += 2) {
        STAGE(kk + 1, A1, X1);            // prefetch under compute
        COMPUTE(A0, X0);
        __syncthreads();                  // A1/X1 ready; A0/X0 reads done
        if (kk + 2 < NKSTEP) STAGE(kk + 2, A0, X0);
        COMPUTE(A1, X1);
        __syncthreads();
    }
    #undef STAGE
    #undef COMPUTE

    // Epilogue: bias + exact GELU + W2 dot; reduce over f.
    const float* b1e = b1 + e * HFD;
    const float* W2e = W2 + e * HFD;
    const float kInvSqrt2 = 0.70710678118654752f;

    float po0 = 0.f, po1 = 0.f;
    #pragma unroll
    for (int m = 0; m < 4; ++m) {
        const int base = mt * 256 + wm * 128 + m * 32 + 4 * hi;
        #pragma unroll
        for (int r = 0; r < 16; ++r) {
            const int frow = base + (r & 3) + 8 * (r >> 2);
            const float bv = b1e[frow];
            const float wv = W2e[frow];
            const float h0 = acc[m][0][r] + bv;
            const float h1 = acc[m][1][r] + bv;
            po0 += 0.5f * h0 * (1.f + erff(h0 * kInvSqrt2)) * wv;
            po1 += 0.5f * h1 * (1.f + erff(h1 * kInvSqrt2)) * wv;
        }
    }
    po0 += __shfl_xor(po0, 32, 64);
    po1 += __shfl_xor(po1, 32, 64);

    if (hi == 0) {
        o_part[wm][wn * 64 + lo5]      = po0;
        o_part[wm][wn * 64 + 32 + lo5] = po1;
    }
    __syncthreads();

    // P accumulation: two M-tiles add disjoint halves? No -- each (e,pt,mt)
    // block owns a distinct partial; the two mt blocks both contribute to the
    // same P row range, so use atomicAdd (exactly 2 commutative adds/row).
    if (tid < nt) {
        atomicAdd(&P[cb + pos0 + tid], o_part[0][tid] + o_part[1][tid]);
    }
}

// ---------------------------------------------------------------------------
// Combine: out[t] = w0 * P[gs0] + w1 * P[gs1].  Deterministic (2 fp adds
// per P entry are commutative-safe: addition order of 2 values is fixed).
// ---------------------------------------------------------------------------
__global__ __launch_bounds__(256)
void combine_kernel(const int* __restrict__ inv,
                    const float* __restrict__ P,
                    const float* __restrict__ wslot,
                    float* __restrict__ out_scores)
{
    const int t = blockIdx.x * 256 + threadIdx.x;
    if (t >= B_TOK) return;
    out_scores[t] = wslot[2 * t]     * P[inv[2 * t]]
                  + wslot[2 * t + 1] * P[inv[2 * t + 1]];
}

// ---------------------------------------------------------------------------
extern "C" void kernel_launch(void* const* d_in, const int* in_sizes, int n_in,
                              void* d_out, int out_size, void* d_ws, size_t ws_size,
                              hipStream_t stream)
{
    const float* x  = (const float*)d_in[0];   // [B, H]
    const float* W1 = (const float*)d_in[1];   // [E, H, HF]
    const float* b1 = (const float*)d_in[2];   // [E, HF]
    const float* W2 = (const float*)d_in[3];   // [E, HF]
    const float* Wg = (const float*)d_in[4];   // [H, E]
    const float* bg = (const float*)d_in[5];   // [E]

    float* out        = (float*)d_out;
    float* out_scores = out;                   // [B, 1]
    float* out_logits = out + B_TOK;           // [B, E]

    char* ws = (char*)d_ws;
    int*            counts = (int*)           (ws + OFF_COUNTS);
    int*            cbase  = (int*)           (ws + OFF_CBASE);
    int*            bucket = (int*)           (ws + OFF_BUCKET);
    float*          wslot  = (float*)         (ws + OFF_WSLOT);
    int*            route  = (int*)           (ws + OFF_ROUTE);
    int*            inv    = (int*)           (ws + OFF_INV);
    float*          WgT    = (float*)         (ws + OFF_WGT);
    float*          P      = (float*)         (ws + OFF_P);
    unsigned short* W1ts   = (unsigned short*)(ws + OFF_W1TS);
    unsigned short* xgT    = (unsigned short*)(ws + OFF_XGT);

    hipMemsetAsync(counts, 0, NE * sizeof(int), stream);
    hipMemsetAsync(P, 0, 33792 * sizeof(float), stream);

    wg_transpose_kernel<<<1, 256, 0, stream>>>(Wg, WgT);

    prep_w1_kernel<<<NE * NKSTEP, 256, 0, stream>>>(W1, W1ts);

    gate_logits_kernel<<<B_TOK / 4, 256, 0, stream>>>(x, WgT, bg, out_logits,
                                                      wslot, route);

    route_kernel<<<B_TOK / 1024, 1024, 0, stream>>>(route, counts, bucket);

    prefix_kernel<<<1, 64, 0, stream>>>(counts, cbase);

    xgather_kernel<<<NE * (B_TOK / 64), 256, 0, stream>>>(
        x, bucket, counts, cbase, xgT, inv);

    expert_mfma_kernel<<<NE * (B_TOK * 2 / TN), 256, 0, stream>>>(
        xgT, W1ts, b1, W2, counts, cbase, P);

    combine_kernel<<<B_TOK / 256, 256, 0, stream>>>(inv, P, wslot, out_scores);
}